// Round 3
// baseline (8591.780 us; speedup 1.0000x reference)
//
#include <hip/hip_runtime.h>
#include <math.h>

#define NWALK 32000
#define NNODE 8000
#define NEDGE 64000

// workspace layout (float offsets)
static const size_t OFF_WL   = 0;                         // 5 * 12288  (wf, wb, m, A, B in chunked layout)
static const size_t OFF_TF   = OFF_WL + 5*12288;          // T_f[8][192]
static const size_t OFF_TB   = OFF_TF + 1536;             // T_b[8][192]
static const size_t OFF_ME   = OFF_TB + 1536;             // M_edge[192][16]
static const size_t OFF_WMHT = OFF_ME + 3072;             // WmhT[64][192]
static const size_t OFF_DMAX = OFF_WMHT + 12288;          // int degmax
static const size_t OFF_E2   = OFF_DMAX + 64;             // E2[64000][192]
static const size_t OFF_H2   = OFF_E2 + (size_t)NEDGE*192;
static const size_t OFF_XGE  = OFF_H2 + (size_t)NNODE*192;
static const size_t OFF_HW   = OFF_XGE + (size_t)NWALK*8*192;

__device__ __forceinline__ float sigm(float x){ return 1.f/(1.f+__expf(-x)); }
__device__ __forceinline__ float tanh_(float x){ float e=__expf(2.f*x); return 1.f-2.f/(e+1.f); }

__global__ void k_init(int* dmax){ if (threadIdx.x==0) *dmax = 0; }

// transpose 5 (192x64) matrices into chunked layout: dst[(k>>2)*768 + row*4 + (k&3)]
__global__ void k_prep_wl(const float* __restrict__ whh_wf, const float* __restrict__ whh_wb,
                          const float* __restrict__ whh_m,  const float* __restrict__ wih_m,
                          float* __restrict__ WL){
  int idx = blockIdx.x*256 + threadIdx.x;
  if (idx >= 5*12288) return;
  int m = idx / 12288, r = idx % 12288;
  int row = r >> 6, k = r & 63;
  float v;
  if      (m==0) v = whh_wf[row*64+k];
  else if (m==1) v = whh_wb[row*64+k];
  else if (m==2) v = whh_m [row*64+k];
  else if (m==3) v = wih_m [row*193 + 64  + k];
  else           v = wih_m [row*193 + 128 + k];
  WL[m*12288 + (k>>2)*768 + row*4 + (k&3)] = v;
}

__global__ void k_prep_tbl(const float* __restrict__ wih_wf, const float* __restrict__ bih_wf,
                           const float* __restrict__ wih_wb, const float* __restrict__ bih_wb,
                           float* __restrict__ Tf, float* __restrict__ Tb){
  int idx = blockIdx.x*256+threadIdx.x;
  if (idx >= 3072) return;
  int which = idx / 1536, r = idx % 1536;
  int u = r / 192, g = r % 192;
  float ang = (float)u * 0.78539816339744831f; // pi/4
  float s = sinf(ang), c = cosf(ang);
  if (which==0) Tf[u*192+g] = bih_wf[g] + wih_wf[g*2+0]*s + wih_wf[g*2+1]*c;
  else          Tb[u*192+g] = bih_wb[g] + wih_wb[g*2+0]*s + wih_wb[g*2+1]*c;
}

__global__ void k_prep_medge_wmht(const float* __restrict__ wih_m, const float* __restrict__ w_edge,
                                  float* __restrict__ M, float* __restrict__ WmhT){
  int idx = blockIdx.x*256+threadIdx.x;
  if (idx < 3072){
    int g = idx >> 4, f = idx & 15;
    float acc = 0.f;
    for (int d=0; d<193; ++d) acc += wih_m[g*193+d]*w_edge[d*16+f];
    M[g*16+f] = acc;
  }
  int j = idx - 3072;
  if (j >= 0 && j < 12288){
    int k = j / 192, g = j % 192;
    WmhT[k*192+g] = wih_m[g*193+k];
  }
}

__global__ void k_degmax(const int* __restrict__ walks, const int* __restrict__ degs,
                         int* __restrict__ dmax){
  int idx = blockIdx.x*256+threadIdx.x;
  int v = 0;
  if (idx < NWALK*8) v = degs[walks[idx]];
  #pragma unroll
  for (int off=32; off; off>>=1) v = max(v, __shfl_xor(v, off));
  if ((threadIdx.x & 63)==0) atomicMax(dmax, v);
}

__global__ void k_e2(const float* __restrict__ e, const float* __restrict__ M,
                     const float* __restrict__ bih_m, float* __restrict__ E2){
  int edge = blockIdx.x;
  int g = threadIdx.x;
  __shared__ float ev[16];
  if (g < 16) ev[g] = e[edge*16+g];
  __syncthreads();
  float acc = bih_m[g];
  #pragma unroll
  for (int f=0; f<16; ++f) acc += ev[f]*M[g*16+f];
  E2[(size_t)edge*192+g] = acc;
}

__global__ void k_h2(const float* __restrict__ h, const float* __restrict__ WmhT,
                     float* __restrict__ H2){
  int node = blockIdx.x; int g = threadIdx.x;
  __shared__ float hv[64];
  if (g < 64) hv[g] = h[node*64+g];
  __syncthreads();
  float acc = 0.f;
  for (int k=0;k<64;++k) acc += hv[k]*WmhT[k*192+g];
  H2[(size_t)node*192+g] = acc;
}

#define DOT4(a,b) ((a).x*(b).x+(a).y*(b).y+(a).z*(b).z+(a).w*(b).w)
// 3-gate matvec for 8 walks: acc{0,1,2}[w] += W rows {lane,64+lane,128+lane} . hbuf[wkb+w]
#define MM3(W4, A0, A1, A2) do { \
  _Pragma("unroll") \
  for (int c=0;c<16;++c){ \
    float4 w0=(W4)[c*192+lane]; \
    float4 w1=(W4)[c*192+64+lane]; \
    float4 w2=(W4)[c*192+128+lane]; \
    _Pragma("unroll") \
    for (int w=0;w<8;++w){ \
      float4 hv=((const float4*)hbuf[wkb+w])[c]; \
      A0[w]+=DOT4(w0,hv); A1[w]+=DOT4(w1,hv); A2[w]+=DOT4(w2,hv); } } \
} while(0)

__global__ __launch_bounds__(512,2) void k_walk(
    const int* __restrict__ walks, const int* __restrict__ degs,
    const float* __restrict__ bhh_wf, const float* __restrict__ bhh_wb,
    const float* __restrict__ bih_m, const float* __restrict__ wih_m,
    const float* __restrict__ WLb, const float* __restrict__ Tf, const float* __restrict__ Tb,
    const int* __restrict__ dmaxp, const float* __restrict__ H2,
    float* __restrict__ XGE, float* __restrict__ HW)
{
  __shared__ __align__(16) float wrec[12288];
  __shared__ __align__(16) float wproj[12288];
  __shared__ __align__(16) float hbuf[64][64];
  __shared__ __align__(16) float tbl[1536];
  __shared__ float sb_bhh[192];
  __shared__ float sb_bihm[192];
  __shared__ float sb_wdeg[192];
  __shared__ int   m_u[64][8];
  __shared__ int   m_n[64][8];
  __shared__ float m_d[64][8];

  const int tid = threadIdx.x;
  const int wave = tid>>6, lane = tid&63;
  const int wkb = wave<<3;           // 8 walks per wave
  const int vbase = blockIdx.x*64;   // 64 walks per block

  { // stage phase-F weights (Whh_wf, A) + tables
    const float4* sW=(const float4*)(WLb);
    const float4* sP=(const float4*)(WLb + 3*12288);
    for (int i=tid;i<3072;i+=512){ ((float4*)wrec)[i]=sW[i]; ((float4*)wproj)[i]=sP[i]; }
    for (int i=tid;i<1536;i+=512) tbl[i]=Tf[i];
    if (tid<192){ sb_bhh[tid]=bhh_wf[tid]; sb_bihm[tid]=bih_m[tid]; sb_wdeg[tid]=wih_m[tid*193+192]; }
  }
  if (tid<64){ // per-walk meta: uniq / node / deg, in GRU-position (reversed) order
    const int v=vbase+tid;
    int w[8];
    #pragma unroll
    for (int i=0;i<8;++i) w[i]=walks[v*8+i];
    int u[8];
    #pragma unroll
    for (int i=0;i<8;++i){
      int ui=i;
      #pragma unroll
      for (int j=7;j>=0;--j) if (j<=i && w[j]==w[i]) ui=j;  // first occurrence
      u[i]=ui;
    }
    const float dmx=(float)(*dmaxp);
    #pragma unroll
    for (int t=0;t<8;++t){
      m_u[tid][t]=u[7-t];
      int nd=w[7-t];
      m_n[tid][t]=nd;
      m_d[tid][t]=(float)degs[nd]/dmx;
    }
  }
  float hst[8], hfs[8];
  #pragma unroll
  for (int w=0;w<8;++w) hst[w]=0.f;
  __syncthreads();

  const float4* WR4=(const float4*)wrec;
  const float4* WP4=(const float4*)wproj;

  // ---- forward walk GRU + A-projection -> XGE partial ----
  for (int t=0;t<8;++t){
    float a0[8],a1[8],a2[8];
    #pragma unroll
    for (int w=0;w<8;++w){ a0[w]=sb_bhh[lane]; a1[w]=sb_bhh[64+lane]; a2[w]=sb_bhh[128+lane]; }
    if (t) MM3(WR4,a0,a1,a2);          // t==0: h==0, matvec is zero
    #pragma unroll
    for (int w=0;w<8;++w){
      const int u=m_u[wkb+w][t];
      const float xr=tbl[u*192+lane], xz=tbl[u*192+64+lane], xn=tbl[u*192+128+lane];
      const float r=sigm(xr+a0[w]);
      const float z=sigm(xz+a1[w]);
      const float n=tanh_(xn+r*a2[w]);
      hst[w]=(1.f-z)*n+z*hst[w];
    }
    __syncthreads();                    // all reads of h_t done
    #pragma unroll
    for (int w=0;w<8;++w) hbuf[wkb+w][lane]=hst[w];
    __syncthreads();                    // h_{t+1} visible
    float p0[8],p1[8],p2[8];
    #pragma unroll
    for (int w=0;w<8;++w){ p0[w]=0.f;p1[w]=0.f;p2[w]=0.f; }
    MM3(WP4,p0,p1,p2);
    #pragma unroll
    for (int w=0;w<8;++w){
      const size_t base=((size_t)(vbase+wkb+w)*8+t)*192;
      XGE[base+lane]=p0[w]; XGE[base+64+lane]=p1[w]; XGE[base+128+lane]=p2[w];
    }
  }
  #pragma unroll
  for (int w=0;w<8;++w) hfs[w]=hst[w];

  // ---- restage (Whh_wb, B, T_b) ----
  __syncthreads();
  {
    const float4* sW=(const float4*)(WLb + 1*12288);
    const float4* sP=(const float4*)(WLb + 4*12288);
    for (int i=tid;i<3072;i+=512){ ((float4*)wrec)[i]=sW[i]; ((float4*)wproj)[i]=sP[i]; }
    for (int i=tid;i<1536;i+=512) tbl[i]=Tb[i];
    if (tid<192) sb_bhh[tid]=bhh_wb[tid];
  }
  #pragma unroll
  for (int w=0;w<8;++w) hst[w]=0.f;
  __syncthreads();

  // ---- backward walk GRU (positions 7..0) + B-projection + finalize XGE ----
  for (int s=0;s<8;++s){
    const int t=7-s;
    float a0[8],a1[8],a2[8];
    #pragma unroll
    for (int w=0;w<8;++w){ a0[w]=sb_bhh[lane]; a1[w]=sb_bhh[64+lane]; a2[w]=sb_bhh[128+lane]; }
    if (s) MM3(WR4,a0,a1,a2);          // s==0: h==0
    #pragma unroll
    for (int w=0;w<8;++w){
      const int u=m_u[wkb+w][t];
      const float xr=tbl[u*192+lane], xz=tbl[u*192+64+lane], xn=tbl[u*192+128+lane];
      const float r=sigm(xr+a0[w]);
      const float z=sigm(xz+a1[w]);
      const float n=tanh_(xn+r*a2[w]);
      hst[w]=(1.f-z)*n+z*hst[w];
    }
    __syncthreads();
    #pragma unroll
    for (int w=0;w<8;++w) hbuf[wkb+w][lane]=hst[w];
    __syncthreads();
    float p0[8],p1[8],p2[8];
    #pragma unroll
    for (int w=0;w<8;++w){ p0[w]=0.f;p1[w]=0.f;p2[w]=0.f; }
    MM3(WP4,p0,p1,p2);
    #pragma unroll
    for (int w=0;w<8;++w){
      const int wk=wkb+w;
      const size_t base=((size_t)(vbase+wk)*8+t)*192;
      const int nd=m_n[wk][t];
      const float dd=m_d[wk][t];
      const size_t h2b=(size_t)nd*192;
      XGE[base+lane]     += p0[w] + H2[h2b+lane]      + dd*sb_wdeg[lane]      + sb_bihm[lane];
      XGE[base+64+lane]  += p1[w] + H2[h2b+64+lane]   + dd*sb_wdeg[64+lane]   + sb_bihm[64+lane];
      XGE[base+128+lane] += p2[w] + H2[h2b+128+lane]  + dd*sb_wdeg[128+lane]  + sb_bihm[128+lane];
    }
  }
  #pragma unroll
  for (int w=0;w<8;++w)
    HW[(size_t)(vbase+wkb+w)*64+lane]=0.5f*(hfs[w]+hst[w]);
}

__global__ __launch_bounds__(512,4) void k_main(
    const int* __restrict__ eids, const float* __restrict__ bhh_m,
    const float* __restrict__ WLm, const float* __restrict__ XGE,
    const float* __restrict__ E2, const float* __restrict__ HW,
    float* __restrict__ out)
{
  __shared__ __align__(16) float wrec[12288];
  __shared__ __align__(16) float hbuf[64][64];
  __shared__ float sb_bhh[192];
  const int tid=threadIdx.x, wave=tid>>6, lane=tid&63;
  const int wkb=wave<<3;
  const int vbase=blockIdx.x*64;
  for (int i=tid;i<3072;i+=512) ((float4*)wrec)[i]=((const float4*)WLm)[i];
  if (tid<192) sb_bhh[tid]=bhh_m[tid];
  float hst[8];
  #pragma unroll
  for (int w=0;w<8;++w){
    hst[w]=HW[(size_t)(vbase+wkb+w)*64+lane];
    hbuf[wkb+w][lane]=hst[w];
  }
  __syncthreads();
  const float4* WR4=(const float4*)wrec;
  for (int t=0;t<15;++t){
    float a0[8],a1[8],a2[8];
    #pragma unroll
    for (int w=0;w<8;++w){ a0[w]=sb_bhh[lane]; a1[w]=sb_bhh[64+lane]; a2[w]=sb_bhh[128+lane]; }
    MM3(WR4,a0,a1,a2);
    #pragma unroll
    for (int w=0;w<8;++w){
      const int v=vbase+wkb+w;
      const float* xg;
      if (t&1) xg = E2 + (size_t)eids[v*7+(t>>1)]*192;
      else     xg = XGE + ((size_t)v*8+(t>>1))*192;
      const float xr=xg[lane], xz=xg[64+lane], xn=xg[128+lane];
      const float r=sigm(xr+a0[w]);
      const float z=sigm(xz+a1[w]);
      const float n=tanh_(xn+r*a2[w]);
      hst[w]=(1.f-z)*n+z*hst[w];
    }
    __syncthreads();                 // all reads of h_t done
    #pragma unroll
    for (int w=0;w<8;++w) hbuf[wkb+w][lane]=hst[w];
    __syncthreads();                 // h_{t+1} visible
  }
  #pragma unroll
  for (int w=0;w<8;++w) out[(size_t)(vbase+wkb+w)*64+lane]=hst[w];
}

extern "C" void kernel_launch(void* const* d_in, const int* in_sizes, int n_in,
                              void* d_out, int out_size, void* d_ws, size_t ws_size,
                              hipStream_t stream)
{
  const float* h      = (const float*)d_in[0];
  const float* e      = (const float*)d_in[2];
  const int*   walks  = (const int*)d_in[3];
  const int*   eids   = (const int*)d_in[4];
  const int*   degs   = (const int*)d_in[5];
  const float* wih_wf = (const float*)d_in[6];
  const float* whh_wf = (const float*)d_in[7];
  const float* bih_wf = (const float*)d_in[8];
  const float* bhh_wf = (const float*)d_in[9];
  const float* wih_wb = (const float*)d_in[10];
  const float* whh_wb = (const float*)d_in[11];
  const float* bih_wb = (const float*)d_in[12];
  const float* bhh_wb = (const float*)d_in[13];
  const float* wih_m  = (const float*)d_in[14];
  const float* whh_m  = (const float*)d_in[15];
  const float* bih_m  = (const float*)d_in[16];
  const float* bhh_m  = (const float*)d_in[17];
  const float* w_edge = (const float*)d_in[18];
  float* out = (float*)d_out;
  float* wsf = (float*)d_ws;

  float* WL   = wsf + OFF_WL;
  float* Tf   = wsf + OFF_TF;
  float* Tb   = wsf + OFF_TB;
  float* Me   = wsf + OFF_ME;
  float* WmhT = wsf + OFF_WMHT;
  int*   dmax = (int*)(wsf + OFF_DMAX);
  float* E2   = wsf + OFF_E2;
  float* H2   = wsf + OFF_H2;
  float* XGE  = wsf + OFF_XGE;
  float* HW   = wsf + OFF_HW;

  hipLaunchKernelGGL(k_init,            dim3(1),    dim3(64), 0, stream, dmax);
  hipLaunchKernelGGL(k_prep_wl,         dim3(240),  dim3(256),0, stream, whh_wf,whh_wb,whh_m,wih_m,WL);
  hipLaunchKernelGGL(k_prep_tbl,        dim3(12),   dim3(256),0, stream, wih_wf,bih_wf,wih_wb,bih_wb,Tf,Tb);
  hipLaunchKernelGGL(k_prep_medge_wmht, dim3(60),   dim3(256),0, stream, wih_m,w_edge,Me,WmhT);
  hipLaunchKernelGGL(k_degmax,          dim3(1000), dim3(256),0, stream, walks,degs,dmax);
  hipLaunchKernelGGL(k_e2,              dim3(NEDGE),dim3(192),0, stream, e,Me,bih_m,E2);
  hipLaunchKernelGGL(k_h2,              dim3(NNODE),dim3(192),0, stream, h,WmhT,H2);
  hipLaunchKernelGGL(k_walk,            dim3(500),  dim3(512),0, stream,
                     walks,degs,bhh_wf,bhh_wb,bih_m,wih_m,WL,Tf,Tb,dmax,H2,XGE,HW);
  hipLaunchKernelGGL(k_main,            dim3(500),  dim3(512),0, stream,
                     eids,bhh_m,WL+2*12288,XGE,E2,HW,out);
  (void)in_sizes;(void)n_in;(void)out_size;(void)ws_size;
}

// Round 4
// 6875.646 us; speedup vs baseline: 1.2496x; 1.2496x over previous
//
#include <hip/hip_runtime.h>
#include <math.h>

#define NWALK 32000
#define NNODE 8000
#define NEDGE 64000

// workspace layout (float offsets)
static const size_t OFF_WL   = 0;                         // 5 * 12288  (wf, wb, m, A, B in chunked layout)
static const size_t OFF_TF   = OFF_WL + 5*12288;          // T_f[8][192]
static const size_t OFF_TB   = OFF_TF + 1536;             // T_b[8][192]
static const size_t OFF_ME   = OFF_TB + 1536;             // M_edge[192][16]
static const size_t OFF_WMHT = OFF_ME + 3072;             // WmhT[64][192]
static const size_t OFF_DMAX = OFF_WMHT + 12288;          // int degmax
static const size_t OFF_E2   = OFF_DMAX + 64;             // E2[64000][192]
static const size_t OFF_H2   = OFF_E2 + (size_t)NEDGE*192;
static const size_t OFF_XGE  = OFF_H2 + (size_t)NNODE*192;
static const size_t OFF_HW   = OFF_XGE + (size_t)NWALK*8*192;

__device__ __forceinline__ float sigm(float x){ return 1.f/(1.f+__expf(-x)); }
__device__ __forceinline__ float tanh_(float x){ float e=__expf(2.f*x); return 1.f-2.f/(e+1.f); }

__global__ void k_init(int* dmax){ if (threadIdx.x==0) *dmax = 0; }

// transpose 5 (192x64) matrices into chunked layout: dst[(k>>2)*768 + row*4 + (k&3)]
__global__ void k_prep_wl(const float* __restrict__ whh_wf, const float* __restrict__ whh_wb,
                          const float* __restrict__ whh_m,  const float* __restrict__ wih_m,
                          float* __restrict__ WL){
  int idx = blockIdx.x*256 + threadIdx.x;
  if (idx >= 5*12288) return;
  int m = idx / 12288, r = idx % 12288;
  int row = r >> 6, k = r & 63;
  float v;
  if      (m==0) v = whh_wf[row*64+k];
  else if (m==1) v = whh_wb[row*64+k];
  else if (m==2) v = whh_m [row*64+k];
  else if (m==3) v = wih_m [row*193 + 64  + k];
  else           v = wih_m [row*193 + 128 + k];
  WL[m*12288 + (k>>2)*768 + row*4 + (k&3)] = v;
}

__global__ void k_prep_tbl(const float* __restrict__ wih_wf, const float* __restrict__ bih_wf,
                           const float* __restrict__ wih_wb, const float* __restrict__ bih_wb,
                           float* __restrict__ Tf, float* __restrict__ Tb){
  int idx = blockIdx.x*256+threadIdx.x;
  if (idx >= 3072) return;
  int which = idx / 1536, r = idx % 1536;
  int u = r / 192, g = r % 192;
  float ang = (float)u * 0.78539816339744831f; // pi/4
  float s = sinf(ang), c = cosf(ang);
  if (which==0) Tf[u*192+g] = bih_wf[g] + wih_wf[g*2+0]*s + wih_wf[g*2+1]*c;
  else          Tb[u*192+g] = bih_wb[g] + wih_wb[g*2+0]*s + wih_wb[g*2+1]*c;
}

__global__ void k_prep_medge_wmht(const float* __restrict__ wih_m, const float* __restrict__ w_edge,
                                  float* __restrict__ M, float* __restrict__ WmhT){
  int idx = blockIdx.x*256+threadIdx.x;
  if (idx < 3072){
    int g = idx >> 4, f = idx & 15;
    float acc = 0.f;
    for (int d=0; d<193; ++d) acc += wih_m[g*193+d]*w_edge[d*16+f];
    M[g*16+f] = acc;
  }
  int j = idx - 3072;
  if (j >= 0 && j < 12288){
    int k = j / 192, g = j % 192;
    WmhT[k*192+g] = wih_m[g*193+k];
  }
}

__global__ void k_degmax(const int* __restrict__ walks, const int* __restrict__ degs,
                         int* __restrict__ dmax){
  int idx = blockIdx.x*256+threadIdx.x;
  int v = 0;
  if (idx < NWALK*8) v = degs[walks[idx]];
  #pragma unroll
  for (int off=32; off; off>>=1) v = max(v, __shfl_xor(v, off));
  if ((threadIdx.x & 63)==0) atomicMax(dmax, v);
}

__global__ void k_e2(const float* __restrict__ e, const float* __restrict__ M,
                     const float* __restrict__ bih_m, float* __restrict__ E2){
  int edge = blockIdx.x;
  int g = threadIdx.x;
  __shared__ float ev[16];
  if (g < 16) ev[g] = e[edge*16+g];
  __syncthreads();
  float acc = bih_m[g];
  #pragma unroll
  for (int f=0; f<16; ++f) acc += ev[f]*M[g*16+f];
  E2[(size_t)edge*192+g] = acc;
}

__global__ void k_h2(const float* __restrict__ h, const float* __restrict__ WmhT,
                     float* __restrict__ H2){
  int node = blockIdx.x; int g = threadIdx.x;
  __shared__ float hv[64];
  if (g < 64) hv[g] = h[node*64+g];
  __syncthreads();
  float acc = 0.f;
  for (int k=0;k<64;++k) acc += hv[k]*WmhT[k*192+g];
  H2[(size_t)node*192+g] = acc;
}

#define DOT4(a,b) ((a).x*(b).x+(a).y*(b).y+(a).z*(b).z+(a).w*(b).w)
// 3-gate matvec for 8 walks: acc{0,1,2}[w] += W rows {lane,64+lane,128+lane} . hbuf[wkb+w]
#define MM3(W4, A0, A1, A2) do { \
  _Pragma("unroll") \
  for (int c=0;c<16;++c){ \
    float4 w0=(W4)[c*192+lane]; \
    float4 w1=(W4)[c*192+64+lane]; \
    float4 w2=(W4)[c*192+128+lane]; \
    _Pragma("unroll") \
    for (int w=0;w<8;++w){ \
      float4 hv=((const float4*)hbuf[wkb+w])[c]; \
      A0[w]+=DOT4(w0,hv); A1[w]+=DOT4(w1,hv); A2[w]+=DOT4(w2,hv); } } \
} while(0)

__global__ __launch_bounds__(512,1) void k_walk(
    const int* __restrict__ walks, const int* __restrict__ degs,
    const float* __restrict__ bhh_wf, const float* __restrict__ bhh_wb,
    const float* __restrict__ bih_m, const float* __restrict__ wih_m,
    const float* __restrict__ WLb, const float* __restrict__ Tf, const float* __restrict__ Tb,
    const int* __restrict__ dmaxp, const float* __restrict__ H2,
    float* __restrict__ XGE, float* __restrict__ HW)
{
  __shared__ __align__(16) float wrec[12288];
  __shared__ __align__(16) float wproj[12288];
  __shared__ __align__(16) float hbuf[64][64];
  __shared__ __align__(16) float tbl[1536];
  __shared__ float sb_bhh[192];
  __shared__ float sb_bihm[192];
  __shared__ float sb_wdeg[192];
  __shared__ int   m_u[64][8];
  __shared__ int   m_n[64][8];
  __shared__ float m_d[64][8];

  const int tid = threadIdx.x;
  const int wave = tid>>6, lane = tid&63;
  const int wkb = wave<<3;           // 8 walks per wave
  const int vbase = blockIdx.x*64;   // 64 walks per block

  { // stage phase-F weights (Whh_wf, A) + tables
    const float4* sW=(const float4*)(WLb);
    const float4* sP=(const float4*)(WLb + 3*12288);
    for (int i=tid;i<3072;i+=512){ ((float4*)wrec)[i]=sW[i]; ((float4*)wproj)[i]=sP[i]; }
    for (int i=tid;i<1536;i+=512) tbl[i]=Tf[i];
    if (tid<192){ sb_bhh[tid]=bhh_wf[tid]; sb_bihm[tid]=bih_m[tid]; sb_wdeg[tid]=wih_m[tid*193+192]; }
  }
  if (tid<64){ // per-walk meta: uniq / node / deg, in GRU-position (reversed) order
    const int v=vbase+tid;
    int w[8];
    #pragma unroll
    for (int i=0;i<8;++i) w[i]=walks[v*8+i];
    int u[8];
    #pragma unroll
    for (int i=0;i<8;++i){
      int ui=i;
      #pragma unroll
      for (int j=7;j>=0;--j) if (j<=i && w[j]==w[i]) ui=j;  // first occurrence
      u[i]=ui;
    }
    const float dmx=(float)(*dmaxp);
    #pragma unroll
    for (int t=0;t<8;++t){
      m_u[tid][t]=u[7-t];
      int nd=w[7-t];
      m_n[tid][t]=nd;
      m_d[tid][t]=(float)degs[nd]/dmx;
    }
  }
  float hst[8], hfs[8];
  #pragma unroll
  for (int w=0;w<8;++w) hst[w]=0.f;
  __syncthreads();

  const float4* WR4=(const float4*)wrec;
  const float4* WP4=(const float4*)wproj;

  // ---- forward walk GRU + A-projection -> XGE partial ----
  for (int t=0;t<8;++t){
    float a0[8],a1[8],a2[8];
    #pragma unroll
    for (int w=0;w<8;++w){ a0[w]=sb_bhh[lane]; a1[w]=sb_bhh[64+lane]; a2[w]=sb_bhh[128+lane]; }
    if (t) MM3(WR4,a0,a1,a2);          // t==0: h==0, matvec is zero
    #pragma unroll
    for (int w=0;w<8;++w){
      const int u=m_u[wkb+w][t];
      const float xr=tbl[u*192+lane], xz=tbl[u*192+64+lane], xn=tbl[u*192+128+lane];
      const float r=sigm(xr+a0[w]);
      const float z=sigm(xz+a1[w]);
      const float n=tanh_(xn+r*a2[w]);
      hst[w]=(1.f-z)*n+z*hst[w];
    }
    __syncthreads();                    // all reads of h_t done
    #pragma unroll
    for (int w=0;w<8;++w) hbuf[wkb+w][lane]=hst[w];
    __syncthreads();                    // h_{t+1} visible
    float p0[8],p1[8],p2[8];
    #pragma unroll
    for (int w=0;w<8;++w){ p0[w]=0.f;p1[w]=0.f;p2[w]=0.f; }
    MM3(WP4,p0,p1,p2);
    #pragma unroll
    for (int w=0;w<8;++w){
      const size_t base=((size_t)(vbase+wkb+w)*8+t)*192;
      XGE[base+lane]=p0[w]; XGE[base+64+lane]=p1[w]; XGE[base+128+lane]=p2[w];
    }
  }
  #pragma unroll
  for (int w=0;w<8;++w) hfs[w]=hst[w];

  // ---- restage (Whh_wb, B, T_b) ----
  __syncthreads();
  {
    const float4* sW=(const float4*)(WLb + 1*12288);
    const float4* sP=(const float4*)(WLb + 4*12288);
    for (int i=tid;i<3072;i+=512){ ((float4*)wrec)[i]=sW[i]; ((float4*)wproj)[i]=sP[i]; }
    for (int i=tid;i<1536;i+=512) tbl[i]=Tb[i];
    if (tid<192) sb_bhh[tid]=bhh_wb[tid];
  }
  #pragma unroll
  for (int w=0;w<8;++w) hst[w]=0.f;
  __syncthreads();

  // ---- backward walk GRU (positions 7..0) + B-projection + finalize XGE ----
  for (int s=0;s<8;++s){
    const int t=7-s;
    float a0[8],a1[8],a2[8];
    #pragma unroll
    for (int w=0;w<8;++w){ a0[w]=sb_bhh[lane]; a1[w]=sb_bhh[64+lane]; a2[w]=sb_bhh[128+lane]; }
    if (s) MM3(WR4,a0,a1,a2);          // s==0: h==0
    #pragma unroll
    for (int w=0;w<8;++w){
      const int u=m_u[wkb+w][t];
      const float xr=tbl[u*192+lane], xz=tbl[u*192+64+lane], xn=tbl[u*192+128+lane];
      const float r=sigm(xr+a0[w]);
      const float z=sigm(xz+a1[w]);
      const float n=tanh_(xn+r*a2[w]);
      hst[w]=(1.f-z)*n+z*hst[w];
    }
    __syncthreads();
    #pragma unroll
    for (int w=0;w<8;++w) hbuf[wkb+w][lane]=hst[w];
    __syncthreads();
    float p0[8],p1[8],p2[8];
    #pragma unroll
    for (int w=0;w<8;++w){ p0[w]=0.f;p1[w]=0.f;p2[w]=0.f; }
    MM3(WP4,p0,p1,p2);
    #pragma unroll
    for (int w=0;w<8;++w){
      const int wk=wkb+w;
      const size_t base=((size_t)(vbase+wk)*8+t)*192;
      const int nd=m_n[wk][t];
      const float dd=m_d[wk][t];
      const size_t h2b=(size_t)nd*192;
      XGE[base+lane]     += p0[w] + H2[h2b+lane]      + dd*sb_wdeg[lane]      + sb_bihm[lane];
      XGE[base+64+lane]  += p1[w] + H2[h2b+64+lane]   + dd*sb_wdeg[64+lane]   + sb_bihm[64+lane];
      XGE[base+128+lane] += p2[w] + H2[h2b+128+lane]  + dd*sb_wdeg[128+lane]  + sb_bihm[128+lane];
    }
  }
  #pragma unroll
  for (int w=0;w<8;++w)
    HW[(size_t)(vbase+wkb+w)*64+lane]=0.5f*(hfs[w]+hst[w]);
}

__global__ __launch_bounds__(512,2) void k_main(
    const int* __restrict__ eids, const float* __restrict__ bhh_m,
    const float* __restrict__ WLm, const float* __restrict__ XGE,
    const float* __restrict__ E2, const float* __restrict__ HW,
    float* __restrict__ out)
{
  __shared__ __align__(16) float wrec[12288];
  __shared__ __align__(16) float hbuf[64][64];
  __shared__ float sb_bhh[192];
  const int tid=threadIdx.x, wave=tid>>6, lane=tid&63;
  const int wkb=wave<<3;
  const int vbase=blockIdx.x*64;
  for (int i=tid;i<3072;i+=512) ((float4*)wrec)[i]=((const float4*)WLm)[i];
  if (tid<192) sb_bhh[tid]=bhh_m[tid];
  float hst[8];
  #pragma unroll
  for (int w=0;w<8;++w){
    hst[w]=HW[(size_t)(vbase+wkb+w)*64+lane];
    hbuf[wkb+w][lane]=hst[w];
  }
  __syncthreads();
  const float4* WR4=(const float4*)wrec;
  for (int t=0;t<15;++t){
    float a0[8],a1[8],a2[8];
    #pragma unroll
    for (int w=0;w<8;++w){ a0[w]=sb_bhh[lane]; a1[w]=sb_bhh[64+lane]; a2[w]=sb_bhh[128+lane]; }
    MM3(WR4,a0,a1,a2);
    #pragma unroll
    for (int w=0;w<8;++w){
      const int v=vbase+wkb+w;
      const float* xg;
      if (t&1) xg = E2 + (size_t)eids[v*7+(t>>1)]*192;
      else     xg = XGE + ((size_t)v*8+(t>>1))*192;
      const float xr=xg[lane], xz=xg[64+lane], xn=xg[128+lane];
      const float r=sigm(xr+a0[w]);
      const float z=sigm(xz+a1[w]);
      const float n=tanh_(xn+r*a2[w]);
      hst[w]=(1.f-z)*n+z*hst[w];
    }
    __syncthreads();                 // all reads of h_t done
    #pragma unroll
    for (int w=0;w<8;++w) hbuf[wkb+w][lane]=hst[w];
    __syncthreads();                 // h_{t+1} visible
  }
  #pragma unroll
  for (int w=0;w<8;++w) out[(size_t)(vbase+wkb+w)*64+lane]=hst[w];
}

extern "C" void kernel_launch(void* const* d_in, const int* in_sizes, int n_in,
                              void* d_out, int out_size, void* d_ws, size_t ws_size,
                              hipStream_t stream)
{
  const float* h      = (const float*)d_in[0];
  const float* e      = (const float*)d_in[2];
  const int*   walks  = (const int*)d_in[3];
  const int*   eids   = (const int*)d_in[4];
  const int*   degs   = (const int*)d_in[5];
  const float* wih_wf = (const float*)d_in[6];
  const float* whh_wf = (const float*)d_in[7];
  const float* bih_wf = (const float*)d_in[8];
  const float* bhh_wf = (const float*)d_in[9];
  const float* wih_wb = (const float*)d_in[10];
  const float* whh_wb = (const float*)d_in[11];
  const float* bih_wb = (const float*)d_in[12];
  const float* bhh_wb = (const float*)d_in[13];
  const float* wih_m  = (const float*)d_in[14];
  const float* whh_m  = (const float*)d_in[15];
  const float* bih_m  = (const float*)d_in[16];
  const float* bhh_m  = (const float*)d_in[17];
  const float* w_edge = (const float*)d_in[18];
  float* out = (float*)d_out;
  float* wsf = (float*)d_ws;

  float* WL   = wsf + OFF_WL;
  float* Tf   = wsf + OFF_TF;
  float* Tb   = wsf + OFF_TB;
  float* Me   = wsf + OFF_ME;
  float* WmhT = wsf + OFF_WMHT;
  int*   dmax = (int*)(wsf + OFF_DMAX);
  float* E2   = wsf + OFF_E2;
  float* H2   = wsf + OFF_H2;
  float* XGE  = wsf + OFF_XGE;
  float* HW   = wsf + OFF_HW;

  hipLaunchKernelGGL(k_init,            dim3(1),    dim3(64), 0, stream, dmax);
  hipLaunchKernelGGL(k_prep_wl,         dim3(240),  dim3(256),0, stream, whh_wf,whh_wb,whh_m,wih_m,WL);
  hipLaunchKernelGGL(k_prep_tbl,        dim3(12),   dim3(256),0, stream, wih_wf,bih_wf,wih_wb,bih_wb,Tf,Tb);
  hipLaunchKernelGGL(k_prep_medge_wmht, dim3(60),   dim3(256),0, stream, wih_m,w_edge,Me,WmhT);
  hipLaunchKernelGGL(k_degmax,          dim3(1000), dim3(256),0, stream, walks,degs,dmax);
  hipLaunchKernelGGL(k_e2,              dim3(NEDGE),dim3(192),0, stream, e,Me,bih_m,E2);
  hipLaunchKernelGGL(k_h2,              dim3(NNODE),dim3(192),0, stream, h,WmhT,H2);
  hipLaunchKernelGGL(k_walk,            dim3(500),  dim3(512),0, stream,
                     walks,degs,bhh_wf,bhh_wb,bih_m,wih_m,WL,Tf,Tb,dmax,H2,XGE,HW);
  hipLaunchKernelGGL(k_main,            dim3(500),  dim3(512),0, stream,
                     eids,bhh_m,WL+2*12288,XGE,E2,HW,out);
  (void)in_sizes;(void)n_in;(void)out_size;(void)ws_size;
}

// Round 6
// 1107.645 us; speedup vs baseline: 7.7568x; 6.2074x over previous
//
#include <hip/hip_runtime.h>
#include <math.h>

#define NWALK 32000
#define NNODE 8000
#define NEDGE 64000

// workspace layout (float offsets)
static const size_t OFF_WL   = 0;                         // 5 * 12288  (wf, wb, m, A, B in chunked layout)
static const size_t OFF_TF   = OFF_WL + 5*12288;          // T_f[8][192]
static const size_t OFF_TB   = OFF_TF + 1536;             // T_b[8][192]
static const size_t OFF_ME   = OFF_TB + 1536;             // M_edge[192][16]
static const size_t OFF_WMHT = OFF_ME + 3072;             // WmhT[64][192]
static const size_t OFF_DMAX = OFF_WMHT + 12288;          // int degmax
static const size_t OFF_E2   = OFF_DMAX + 64;             // E2[64000][192]
static const size_t OFF_H2   = OFF_E2 + (size_t)NEDGE*192;
static const size_t OFF_XGE  = OFF_H2 + (size_t)NNODE*192;
static const size_t OFF_HW   = OFF_XGE + (size_t)NWALK*8*192;

__device__ __forceinline__ float sigm(float x){ return 1.f/(1.f+__expf(-x)); }
__device__ __forceinline__ float tanh_(float x){ float e=__expf(2.f*x); return 1.f-2.f/(e+1.f); }

__global__ void k_init(int* dmax){ if (threadIdx.x==0) *dmax = 0; }

// transpose 5 (192x64) matrices into chunked layout: dst[(k>>2)*768 + row*4 + (k&3)]
__global__ void k_prep_wl(const float* __restrict__ whh_wf, const float* __restrict__ whh_wb,
                          const float* __restrict__ whh_m,  const float* __restrict__ wih_m,
                          float* __restrict__ WL){
  int idx = blockIdx.x*256 + threadIdx.x;
  if (idx >= 5*12288) return;
  int m = idx / 12288, r = idx % 12288;
  int row = r >> 6, k = r & 63;
  float v;
  if      (m==0) v = whh_wf[row*64+k];
  else if (m==1) v = whh_wb[row*64+k];
  else if (m==2) v = whh_m [row*64+k];
  else if (m==3) v = wih_m [row*193 + 64  + k];
  else           v = wih_m [row*193 + 128 + k];
  WL[m*12288 + (k>>2)*768 + row*4 + (k&3)] = v;
}

__global__ void k_prep_tbl(const float* __restrict__ wih_wf, const float* __restrict__ bih_wf,
                           const float* __restrict__ wih_wb, const float* __restrict__ bih_wb,
                           float* __restrict__ Tf, float* __restrict__ Tb){
  int idx = blockIdx.x*256+threadIdx.x;
  if (idx >= 3072) return;
  int which = idx / 1536, r = idx % 1536;
  int u = r / 192, g = r % 192;
  float ang = (float)u * 0.78539816339744831f; // pi/4
  float s = sinf(ang), c = cosf(ang);
  if (which==0) Tf[u*192+g] = bih_wf[g] + wih_wf[g*2+0]*s + wih_wf[g*2+1]*c;
  else          Tb[u*192+g] = bih_wb[g] + wih_wb[g*2+0]*s + wih_wb[g*2+1]*c;
}

__global__ void k_prep_medge_wmht(const float* __restrict__ wih_m, const float* __restrict__ w_edge,
                                  float* __restrict__ M, float* __restrict__ WmhT){
  int idx = blockIdx.x*256+threadIdx.x;
  if (idx < 3072){
    int g = idx >> 4, f = idx & 15;
    float acc = 0.f;
    for (int d=0; d<193; ++d) acc += wih_m[g*193+d]*w_edge[d*16+f];
    M[g*16+f] = acc;
  }
  int j = idx - 3072;
  if (j >= 0 && j < 12288){
    int k = j / 192, g = j % 192;
    WmhT[k*192+g] = wih_m[g*193+k];
  }
}

__global__ void k_degmax(const int* __restrict__ walks, const int* __restrict__ degs,
                         int* __restrict__ dmax){
  int idx = blockIdx.x*256+threadIdx.x;
  int v = 0;
  if (idx < NWALK*8) v = degs[walks[idx]];
  #pragma unroll
  for (int off=32; off; off>>=1) v = max(v, __shfl_xor(v, off));
  if ((threadIdx.x & 63)==0) atomicMax(dmax, v);
}

__global__ void k_e2(const float* __restrict__ e, const float* __restrict__ M,
                     const float* __restrict__ bih_m, float* __restrict__ E2){
  int edge = blockIdx.x;
  int g = threadIdx.x;
  __shared__ float ev[16];
  if (g < 16) ev[g] = e[edge*16+g];
  __syncthreads();
  float acc = bih_m[g];
  #pragma unroll
  for (int f=0; f<16; ++f) acc += ev[f]*M[g*16+f];
  E2[(size_t)edge*192+g] = acc;
}

__global__ void k_h2(const float* __restrict__ h, const float* __restrict__ WmhT,
                     float* __restrict__ H2){
  int node = blockIdx.x; int g = threadIdx.x;
  __shared__ float hv[64];
  if (g < 64) hv[g] = h[node*64+g];
  __syncthreads();
  float acc = 0.f;
  for (int k=0;k<64;++k) acc += hv[k]*WmhT[k*192+g];
  H2[(size_t)node*192+g] = acc;
}

#define DOT4(a,b) ((a).x*(b).x+(a).y*(b).y+(a).z*(b).z+(a).w*(b).w)
// 3-gate matvec for 4 walks: acc{0,1,2}[w] += W rows {lane,64+lane,128+lane} . hbuf[wkb+w]
// unroll 4 (not 16): keeps weight-load live ranges short -> no VGPR spill
#define MM3(W4, A0, A1, A2) do { \
  _Pragma("unroll 4") \
  for (int c=0;c<16;++c){ \
    float4 w0=(W4)[c*192+lane]; \
    float4 w1=(W4)[c*192+64+lane]; \
    float4 w2=(W4)[c*192+128+lane]; \
    _Pragma("unroll") \
    for (int w=0;w<4;++w){ \
      float4 hv=((const float4*)hbuf[wkb+w])[c]; \
      A0[w]+=DOT4(w0,hv); A1[w]+=DOT4(w1,hv); A2[w]+=DOT4(w2,hv); } } \
} while(0)

__global__ __launch_bounds__(512,2) void k_walk(
    const int* __restrict__ walks, const int* __restrict__ degs,
    const float* __restrict__ bhh_wf, const float* __restrict__ bhh_wb,
    const float* __restrict__ bih_m, const float* __restrict__ wih_m,
    const float* __restrict__ WLb, const float* __restrict__ Tf, const float* __restrict__ Tb,
    const int* __restrict__ dmaxp, const float* __restrict__ H2,
    float* __restrict__ XGE, float* __restrict__ HW)
{
  __shared__ __align__(16) float wrec[12288];
  __shared__ __align__(16) float wproj[12288];
  __shared__ __align__(16) float hbuf[32][64];
  __shared__ __align__(16) float tbl[1536];
  __shared__ float sb_bhh[192];
  __shared__ float sb_bihm[192];
  __shared__ float sb_wdeg[192];
  __shared__ int   m_u[32][8];
  __shared__ int   m_n[32][8];
  __shared__ float m_d[32][8];

  const int tid = threadIdx.x;
  const int wave = tid>>6, lane = tid&63;
  const int wkb = wave<<2;           // 4 walks per wave
  const int vbase = blockIdx.x*32;   // 32 walks per block

  { // stage phase-F weights (Whh_wf, A) + tables
    const float4* sW=(const float4*)(WLb);
    const float4* sP=(const float4*)(WLb + 3*12288);
    for (int i=tid;i<3072;i+=512){ ((float4*)wrec)[i]=sW[i]; ((float4*)wproj)[i]=sP[i]; }
    for (int i=tid;i<1536;i+=512) tbl[i]=Tf[i];
    if (tid<192){ sb_bhh[tid]=bhh_wf[tid]; sb_bihm[tid]=bih_m[tid]; sb_wdeg[tid]=wih_m[tid*193+192]; }
  }
  if (tid<32){ // per-walk meta: uniq / node / deg, in GRU-position (reversed) order
    const int v=vbase+tid;
    int w[8];
    #pragma unroll
    for (int i=0;i<8;++i) w[i]=walks[v*8+i];
    int u[8];
    #pragma unroll
    for (int i=0;i<8;++i){
      int ui=i;
      #pragma unroll
      for (int j=7;j>=0;--j) if (j<=i && w[j]==w[i]) ui=j;  // first occurrence
      u[i]=ui;
    }
    const float dmx=(float)(*dmaxp);
    #pragma unroll
    for (int t=0;t<8;++t){
      m_u[tid][t]=u[7-t];
      int nd=w[7-t];
      m_n[tid][t]=nd;
      m_d[tid][t]=(float)degs[nd]/dmx;
    }
  }
  float hst[4], hfs[4];
  #pragma unroll
  for (int w=0;w<4;++w) hst[w]=0.f;
  __syncthreads();

  const float4* WR4=(const float4*)wrec;
  const float4* WP4=(const float4*)wproj;

  // ---- forward walk GRU + A-projection -> XGE partial ----
  for (int t=0;t<8;++t){
    float a0[4],a1[4],a2[4];
    #pragma unroll
    for (int w=0;w<4;++w){ a0[w]=sb_bhh[lane]; a1[w]=sb_bhh[64+lane]; a2[w]=sb_bhh[128+lane]; }
    if (t) MM3(WR4,a0,a1,a2);          // t==0: h==0, matvec is zero
    #pragma unroll
    for (int w=0;w<4;++w){
      const int u=m_u[wkb+w][t];
      const float xr=tbl[u*192+lane], xz=tbl[u*192+64+lane], xn=tbl[u*192+128+lane];
      const float r=sigm(xr+a0[w]);
      const float z=sigm(xz+a1[w]);
      const float n=tanh_(xn+r*a2[w]);
      hst[w]=(1.f-z)*n+z*hst[w];
    }
    __syncthreads();                    // all reads of h_t done
    #pragma unroll
    for (int w=0;w<4;++w) hbuf[wkb+w][lane]=hst[w];
    __syncthreads();                    // h_{t+1} visible
    float p0[4],p1[4],p2[4];
    #pragma unroll
    for (int w=0;w<4;++w){ p0[w]=0.f;p1[w]=0.f;p2[w]=0.f; }
    MM3(WP4,p0,p1,p2);
    #pragma unroll
    for (int w=0;w<4;++w){
      const size_t base=((size_t)(vbase+wkb+w)*8+t)*192;
      XGE[base+lane]=p0[w]; XGE[base+64+lane]=p1[w]; XGE[base+128+lane]=p2[w];
    }
  }
  #pragma unroll
  for (int w=0;w<4;++w) hfs[w]=hst[w];

  // ---- restage (Whh_wb, B, T_b) ----
  __syncthreads();
  {
    const float4* sW=(const float4*)(WLb + 1*12288);
    const float4* sP=(const float4*)(WLb + 4*12288);
    for (int i=tid;i<3072;i+=512){ ((float4*)wrec)[i]=sW[i]; ((float4*)wproj)[i]=sP[i]; }
    for (int i=tid;i<1536;i+=512) tbl[i]=Tb[i];
    if (tid<192) sb_bhh[tid]=bhh_wb[tid];
  }
  #pragma unroll
  for (int w=0;w<4;++w) hst[w]=0.f;
  __syncthreads();

  // ---- backward walk GRU (positions 7..0) + B-projection + finalize XGE ----
  for (int s=0;s<8;++s){
    const int t=7-s;
    float a0[4],a1[4],a2[4];
    #pragma unroll
    for (int w=0;w<4;++w){ a0[w]=sb_bhh[lane]; a1[w]=sb_bhh[64+lane]; a2[w]=sb_bhh[128+lane]; }
    if (s) MM3(WR4,a0,a1,a2);          // s==0: h==0
    #pragma unroll
    for (int w=0;w<4;++w){
      const int u=m_u[wkb+w][t];
      const float xr=tbl[u*192+lane], xz=tbl[u*192+64+lane], xn=tbl[u*192+128+lane];
      const float r=sigm(xr+a0[w]);
      const float z=sigm(xz+a1[w]);
      const float n=tanh_(xn+r*a2[w]);
      hst[w]=(1.f-z)*n+z*hst[w];
    }
    __syncthreads();
    #pragma unroll
    for (int w=0;w<4;++w) hbuf[wkb+w][lane]=hst[w];
    __syncthreads();
    float p0[4],p1[4],p2[4];
    #pragma unroll
    for (int w=0;w<4;++w){ p0[w]=0.f;p1[w]=0.f;p2[w]=0.f; }
    MM3(WP4,p0,p1,p2);
    #pragma unroll
    for (int w=0;w<4;++w){
      const int wk=wkb+w;
      const size_t base=((size_t)(vbase+wk)*8+t)*192;
      const int nd=m_n[wk][t];
      const float dd=m_d[wk][t];
      const size_t h2b=(size_t)nd*192;
      XGE[base+lane]     += p0[w] + H2[h2b+lane]      + dd*sb_wdeg[lane]      + sb_bihm[lane];
      XGE[base+64+lane]  += p1[w] + H2[h2b+64+lane]   + dd*sb_wdeg[64+lane]   + sb_bihm[64+lane];
      XGE[base+128+lane] += p2[w] + H2[h2b+128+lane]  + dd*sb_wdeg[128+lane]  + sb_bihm[128+lane];
    }
  }
  #pragma unroll
  for (int w=0;w<4;++w)
    HW[(size_t)(vbase+wkb+w)*64+lane]=0.5f*(hfs[w]+hst[w]);
}

__global__ __launch_bounds__(512,2) void k_main(
    const int* __restrict__ eids, const float* __restrict__ bhh_m,
    const float* __restrict__ WLm, const float* __restrict__ XGE,
    const float* __restrict__ E2, const float* __restrict__ HW,
    float* __restrict__ out)
{
  __shared__ __align__(16) float wrec[12288];
  __shared__ __align__(16) float hbuf[32][64];
  __shared__ float sb_bhh[192];
  const int tid=threadIdx.x, wave=tid>>6, lane=tid&63;
  const int wkb=wave<<2;             // 4 walks per wave
  const int vbase=blockIdx.x*32;     // 32 walks per block
  for (int i=tid;i<3072;i+=512) ((float4*)wrec)[i]=((const float4*)WLm)[i];
  if (tid<192) sb_bhh[tid]=bhh_m[tid];
  float hst[4];
  #pragma unroll
  for (int w=0;w<4;++w){
    hst[w]=HW[(size_t)(vbase+wkb+w)*64+lane];
    hbuf[wkb+w][lane]=hst[w];
  }
  __syncthreads();
  const float4* WR4=(const float4*)wrec;
  for (int t=0;t<15;++t){
    float a0[4],a1[4],a2[4];
    #pragma unroll
    for (int w=0;w<4;++w){ a0[w]=sb_bhh[lane]; a1[w]=sb_bhh[64+lane]; a2[w]=sb_bhh[128+lane]; }
    MM3(WR4,a0,a1,a2);
    #pragma unroll
    for (int w=0;w<4;++w){
      const int v=vbase+wkb+w;
      const float* xg;
      if (t&1) xg = E2 + (size_t)eids[v*7+(t>>1)]*192;
      else     xg = XGE + ((size_t)v*8+(t>>1))*192;
      const float xr=xg[lane], xz=xg[64+lane], xn=xg[128+lane];
      const float r=sigm(xr+a0[w]);
      const float z=sigm(xz+a1[w]);
      const float n=tanh_(xn+r*a2[w]);
      hst[w]=(1.f-z)*n+z*hst[w];
    }
    __syncthreads();                 // all reads of h_t done
    #pragma unroll
    for (int w=0;w<4;++w) hbuf[wkb+w][lane]=hst[w];
    __syncthreads();                 // h_{t+1} visible
  }
  #pragma unroll
  for (int w=0;w<4;++w) out[(size_t)(vbase+wkb+w)*64+lane]=hst[w];
}

extern "C" void kernel_launch(void* const* d_in, const int* in_sizes, int n_in,
                              void* d_out, int out_size, void* d_ws, size_t ws_size,
                              hipStream_t stream)
{
  const float* h      = (const float*)d_in[0];
  const float* e      = (const float*)d_in[2];
  const int*   walks  = (const int*)d_in[3];
  const int*   eids   = (const int*)d_in[4];
  const int*   degs   = (const int*)d_in[5];
  const float* wih_wf = (const float*)d_in[6];
  const float* whh_wf = (const float*)d_in[7];
  const float* bih_wf = (const float*)d_in[8];
  const float* bhh_wf = (const float*)d_in[9];
  const float* wih_wb = (const float*)d_in[10];
  const float* whh_wb = (const float*)d_in[11];
  const float* bih_wb = (const float*)d_in[12];
  const float* bhh_wb = (const float*)d_in[13];
  const float* wih_m  = (const float*)d_in[14];
  const float* whh_m  = (const float*)d_in[15];
  const float* bih_m  = (const float*)d_in[16];
  const float* bhh_m  = (const float*)d_in[17];
  const float* w_edge = (const float*)d_in[18];
  float* out = (float*)d_out;
  float* wsf = (float*)d_ws;

  float* WL   = wsf + OFF_WL;
  float* Tf   = wsf + OFF_TF;
  float* Tb   = wsf + OFF_TB;
  float* Me   = wsf + OFF_ME;
  float* WmhT = wsf + OFF_WMHT;
  int*   dmax = (int*)(wsf + OFF_DMAX);
  float* E2   = wsf + OFF_E2;
  float* H2   = wsf + OFF_H2;
  float* XGE  = wsf + OFF_XGE;
  float* HW   = wsf + OFF_HW;

  hipLaunchKernelGGL(k_init,            dim3(1),    dim3(64), 0, stream, dmax);
  hipLaunchKernelGGL(k_prep_wl,         dim3(240),  dim3(256),0, stream, whh_wf,whh_wb,whh_m,wih_m,WL);
  hipLaunchKernelGGL(k_prep_tbl,        dim3(12),   dim3(256),0, stream, wih_wf,bih_wf,wih_wb,bih_wb,Tf,Tb);
  hipLaunchKernelGGL(k_prep_medge_wmht, dim3(60),   dim3(256),0, stream, wih_m,w_edge,Me,WmhT);
  hipLaunchKernelGGL(k_degmax,          dim3(1000), dim3(256),0, stream, walks,degs,dmax);
  hipLaunchKernelGGL(k_e2,              dim3(NEDGE),dim3(192),0, stream, e,Me,bih_m,E2);
  hipLaunchKernelGGL(k_h2,              dim3(NNODE),dim3(192),0, stream, h,WmhT,H2);
  hipLaunchKernelGGL(k_walk,            dim3(1000), dim3(512),0, stream,
                     walks,degs,bhh_wf,bhh_wb,bih_m,wih_m,WL,Tf,Tb,dmax,H2,XGE,HW);
  hipLaunchKernelGGL(k_main,            dim3(1000), dim3(512),0, stream,
                     eids,bhh_m,WL+2*12288,XGE,E2,HW,out);
  (void)in_sizes;(void)n_in;(void)out_size;(void)ws_size;
}